// Round 1
// baseline (865.564 us; speedup 1.0000x reference)
//
#include <hip/hip_runtime.h>
#include <math.h>

#define BB 256
#define LL 256
#define HH 1024
#define NH 16
#define DD 64
#define SCALE 0.5f
#define LN_EPS 1e-5f
#define NEG_BIG (-3.402823466e38f)

// ---------------------------------------------------------------------------
// K1: qT[j][b] = sum_i query[b][i]*Wq[j][i] + bq[j]   (transposed for K2's
// scalar loads).  grid (64,16), block 256 = 16 b x 16 j.
// ---------------------------------------------------------------------------
__global__ __launch_bounds__(256) void k1_qproj(const float* __restrict__ query,
                                                const float* __restrict__ Wq,
                                                const float* __restrict__ bq,
                                                float* __restrict__ qT) {
  const int b = (blockIdx.y << 4) + (threadIdx.x & 15);
  const int j = (blockIdx.x << 4) + (threadIdx.x >> 4);
  const float4* q4 = (const float4*)(query + (size_t)b * HH);
  const float4* w4 = (const float4*)(Wq + (size_t)j * HH);
  float acc = 0.f;
#pragma unroll 8
  for (int i = 0; i < HH / 4; i++) {
    float4 a = q4[i], w = w4[i];
    acc += a.x * w.x + a.y * w.y + a.z * w.z + a.w * w.w;
  }
  qT[j * BB + b] = acc + bq[j];
}

// ---------------------------------------------------------------------------
// K2: qkT[b][gu][h][i&3] = SCALE * sum_d qT[h*64+d][b] * Wk[h*64+d][i]
// layout: qkT[b*16384 + (i>>2)*64 + h*4 + (i&3)]  (contiguous 64 floats per
// 4-dim unit -> scalar dwordx16 loads in K3).
// grid (16 itile, 16 h), block 256 = 64 i x 4 bgroups; each thread 64 b's.
// ---------------------------------------------------------------------------
__global__ __launch_bounds__(256) void k2_qk(const float* __restrict__ qT,
                                             const float* __restrict__ Wk,
                                             float* __restrict__ qkT) {
  const int h = blockIdx.y;
  const int it = blockIdx.x;
  const int il = threadIdx.x & 63;
  const int bg = threadIdx.x >> 6;
  const int i = it * 64 + il;
  const int boff = bg * 64;
  float acc[64];
#pragma unroll
  for (int k = 0; k < 64; k++) acc[k] = 0.f;
  for (int d = 0; d < DD; d++) {
    float wv = Wk[(size_t)(h * DD + d) * HH + i];
    const float* qrow = qT + (h * DD + d) * BB + boff;  // wave-uniform -> s_load
#pragma unroll
    for (int k = 0; k < 64; k++) acc[k] = fmaf(qrow[k], wv, acc[k]);
  }
  const int gu = i >> 2, i3 = i & 3;
#pragma unroll
  for (int k = 0; k < 64; k++)
    qkT[(size_t)(boff + k) * (HH * NH / 64) * 64 + gu * 64 + h * 4 + i3] =
        SCALE * acc[k];
}

// ---------------------------------------------------------------------------
// K3: per-batch fused scores -> softmax -> attn-out -> vbar.
// grid 256 (one block per b, 1 block/CU), block 256 (4 waves).
// Phase A: thread t owns key row t; key staged in LDS 64-dim tiles,
//   XOR-swizzled in 16B units (stored[r][c] = logical[r][c ^ (r&15)]) to kill
//   the 64-way bank conflict of row-major [256][64] f32.
//   Wave w stages exactly rows [64w,64w+64) -> no barriers in phase A.
// Phase B: thread t owns dims [4t,4t+4); perfectly coalesced value stream,
//   attn weights broadcast from LDS.
// ---------------------------------------------------------------------------
__global__ __launch_bounds__(256, 1) void k3_attn(
    const float* __restrict__ key, const float* __restrict__ value,
    const int* __restrict__ mask, const float* __restrict__ qkT,
    float* __restrict__ attnOut, float* __restrict__ vbar) {
  __shared__ __align__(16) float kbuf[2][16384];  // 2 x 64KB
  __shared__ float red[32];
  const int b = blockIdx.x;
  const int t = threadIdx.x;
  const int w = t >> 6, ln = t & 63;
  const float* keyb = key + (size_t)b * LL * HH;
  const float* qkb = qkT + (size_t)b * 16384;

  float acc[NH];
#pragma unroll
  for (int h = 0; h < NH; h++) acc[h] = 0.f;

  const int rl4 = ln >> 4, c = ln & 15;

  // prologue: load tile 0 into regs (source-side XOR so LDS dest is linear)
  float4 g[16];
#pragma unroll
  for (int j = 0; j < 16; j++) {
    int r = 64 * w + j * 4 + rl4;
    int u = c ^ (r & 15);
    g[j] = *(const float4*)(keyb + (size_t)r * HH + 4 * u);
  }

  int buf = 0;
  for (int tile = 0; tile < 16; tile++) {
    float* kb = kbuf[buf];
#pragma unroll
    for (int j = 0; j < 16; j++)
      *(float4*)(kb + (size_t)(1024 * w + j * 64 + ln) * 4) = g[j];
    if (tile < 15) {
      const int i0n = (tile + 1) * 64;
#pragma unroll
      for (int j = 0; j < 16; j++) {
        int r = 64 * w + j * 4 + rl4;
        int u = c ^ (r & 15);
        g[j] = *(const float4*)(keyb + (size_t)r * HH + i0n + 4 * u);
      }
    }
    // compute: acc[h] += key[t][i] * qk[i][h] over this 64-dim tile
    const float* qkc = qkb + tile * 16 * 64;
    const int tb = t * 16, tx = t & 15;
#pragma unroll
    for (int u = 0; u < 16; u++) {
      float4 kv = *(const float4*)(kb + (size_t)(tb + (u ^ tx)) * 4);
      const float* qc = qkc + u * 64;  // wave-uniform -> s_load
#pragma unroll
      for (int h = 0; h < NH; h++) {
        acc[h] = fmaf(kv.x, qc[h * 4 + 0], acc[h]);
        acc[h] = fmaf(kv.y, qc[h * 4 + 1], acc[h]);
        acc[h] = fmaf(kv.z, qc[h * 4 + 2], acc[h]);
        acc[h] = fmaf(kv.w, qc[h * 4 + 3], acc[h]);
      }
    }
    buf ^= 1;
  }

  // ---- softmax over l (rows distributed 1/thread) ----
  const int masked = mask[b * LL + t];
  float* scl = kbuf[0];  // 16 x 256 scores
#pragma unroll
  for (int h = 0; h < NH; h++) {
    float s = masked ? NEG_BIG : acc[h];
    acc[h] = s;
    scl[h * LL + t] = s;
  }
  __syncthreads();
#pragma unroll
  for (int hh = 0; hh < 4; hh++) {
    int h = w * 4 + hh;
    float4 v = *(const float4*)(scl + h * LL + ln * 4);
    float m = fmaxf(fmaxf(v.x, v.y), fmaxf(v.z, v.w));
#pragma unroll
    for (int off = 32; off >= 1; off >>= 1) m = fmaxf(m, __shfl_xor(m, off));
    float e = __expf(v.x - m) + __expf(v.y - m) + __expf(v.z - m) +
              __expf(v.w - m);
#pragma unroll
    for (int off = 32; off >= 1; off >>= 1) e += __shfl_xor(e, off);
    if (ln == 0) {
      red[h] = m;
      red[16 + h] = 1.0f / e;
    }
  }
  __syncthreads();
  float* attnT = kbuf[1];  // [l][h]
#pragma unroll
  for (int h = 0; h < NH; h++) {
    float a = masked ? 0.f : __expf(acc[h] - red[h]) * red[16 + h];
    attnT[t * 16 + h] = a;
    attnOut[(size_t)(b * NH + h) * LL + t] = a;
  }
  __syncthreads();

  // ---- phase B: vbar[b][h][4t..4t+3] = sum_l attn[h][l] * value[b][l][4t..]
  float4 acc2[NH];
#pragma unroll
  for (int h = 0; h < NH; h++) acc2[h] = make_float4(0.f, 0.f, 0.f, 0.f);
  const float* valb = value + (size_t)b * LL * HH + 4 * t;
#pragma unroll 8
  for (int l = 0; l < LL; l++) {
    float4 vv = *(const float4*)(valb + (size_t)l * HH);
    const float* ar = attnT + l * 16;
    float4 a0 = *(const float4*)(ar);
    float4 a1 = *(const float4*)(ar + 4);
    float4 a2 = *(const float4*)(ar + 8);
    float4 a3 = *(const float4*)(ar + 12);
    float av[16] = {a0.x, a0.y, a0.z, a0.w, a1.x, a1.y, a1.z, a1.w,
                    a2.x, a2.y, a2.z, a2.w, a3.x, a3.y, a3.z, a3.w};
#pragma unroll
    for (int h = 0; h < NH; h++) {
      acc2[h].x = fmaf(av[h], vv.x, acc2[h].x);
      acc2[h].y = fmaf(av[h], vv.y, acc2[h].y);
      acc2[h].z = fmaf(av[h], vv.z, acc2[h].z);
      acc2[h].w = fmaf(av[h], vv.w, acc2[h].w);
    }
  }
  float* vb = vbar + (size_t)b * 16384 + 4 * t;
#pragma unroll
  for (int h = 0; h < NH; h++) *(float4*)(vb + h * HH) = acc2[h];
}

// ---------------------------------------------------------------------------
// K4: ctx[b][j] = sum_i vbar[b][j>>6][i] * Wv[j][i] + bv[j]
// ---------------------------------------------------------------------------
__global__ __launch_bounds__(256) void k4_ctx(const float* __restrict__ vbar,
                                              const float* __restrict__ Wv,
                                              const float* __restrict__ bv,
                                              float* __restrict__ ctx) {
  const int b = (blockIdx.y << 4) + (threadIdx.x & 15);
  const int j = (blockIdx.x << 4) + (threadIdx.x >> 4);
  const float4* a4 = (const float4*)(vbar + (size_t)b * 16384 + (j >> 6) * HH);
  const float4* w4 = (const float4*)(Wv + (size_t)j * HH);
  float acc = 0.f;
#pragma unroll 8
  for (int i = 0; i < HH / 4; i++) {
    float4 a = a4[i], w = w4[i];
    acc += a.x * w.x + a.y * w.y + a.z * w.z + a.w * w.w;
  }
  ctx[b * HH + j] = acc + bv[j];
}

// ---------------------------------------------------------------------------
// K5: x[b][j] = query[b][j] + sum_i ctx[b][i]*Wf[j][i] + bf[j]
// ---------------------------------------------------------------------------
__global__ __launch_bounds__(256) void k5_outproj(const float* __restrict__ ctx,
                                                  const float* __restrict__ Wf,
                                                  const float* __restrict__ bf,
                                                  const float* __restrict__ query,
                                                  float* __restrict__ xws) {
  const int b = (blockIdx.y << 4) + (threadIdx.x & 15);
  const int j = (blockIdx.x << 4) + (threadIdx.x >> 4);
  const float4* a4 = (const float4*)(ctx + (size_t)b * HH);
  const float4* w4 = (const float4*)(Wf + (size_t)j * HH);
  float acc = 0.f;
#pragma unroll 8
  for (int i = 0; i < HH / 4; i++) {
    float4 a = a4[i], w = w4[i];
    acc += a.x * w.x + a.y * w.y + a.z * w.z + a.w * w.w;
  }
  xws[b * HH + j] = acc + bf[j] + query[(size_t)b * HH + j];
}

// ---------------------------------------------------------------------------
// K6: LayerNorm over H, two-pass (exact), block per b.
// ---------------------------------------------------------------------------
__global__ __launch_bounds__(256) void k6_ln(const float* __restrict__ xws,
                                             const float* __restrict__ gamma,
                                             const float* __restrict__ beta,
                                             float* __restrict__ out0) {
  __shared__ float rb[8];
  const int b = blockIdx.x, t = threadIdx.x;
  float4 v = *(const float4*)(xws + (size_t)b * HH + 4 * t);
  float s = v.x + v.y + v.z + v.w;
#pragma unroll
  for (int off = 32; off >= 1; off >>= 1) s += __shfl_xor(s, off);
  if ((t & 63) == 0) rb[t >> 6] = s;
  __syncthreads();
  float mu = (rb[0] + rb[1] + rb[2] + rb[3]) * (1.0f / HH);
  float dx = v.x - mu, dy = v.y - mu, dz = v.z - mu, dw = v.w - mu;
  float q = dx * dx + dy * dy + dz * dz + dw * dw;
#pragma unroll
  for (int off = 32; off >= 1; off >>= 1) q += __shfl_xor(q, off);
  if ((t & 63) == 0) rb[4 + (t >> 6)] = q;
  __syncthreads();
  float var = (rb[4] + rb[5] + rb[6] + rb[7]) * (1.0f / HH);
  float rs = rsqrtf(var + LN_EPS);
  float4 gm = *(const float4*)(gamma + 4 * t);
  float4 bt = *(const float4*)(beta + 4 * t);
  float4 o;
  o.x = dx * rs * gm.x + bt.x;
  o.y = dy * rs * gm.y + bt.y;
  o.z = dz * rs * gm.z + bt.z;
  o.w = dw * rs * gm.w + bt.w;
  *(float4*)(out0 + (size_t)b * HH + 4 * t) = o;
}

extern "C" void kernel_launch(void* const* d_in, const int* in_sizes, int n_in,
                              void* d_out, int out_size, void* d_ws,
                              size_t ws_size, hipStream_t stream) {
  (void)in_sizes; (void)n_in; (void)out_size; (void)ws_size;
  const float* key = (const float*)d_in[0];
  const float* value = (const float*)d_in[1];
  const float* query = (const float*)d_in[2];
  const int* mask = (const int*)d_in[3];
  const float* Wq = (const float*)d_in[4];
  const float* bq = (const float*)d_in[5];
  const float* Wk = (const float*)d_in[6];
  // d_in[7] = bk: constant per (b,h) score shift -> softmax-invariant, dropped
  const float* Wv = (const float*)d_in[8];
  const float* bv = (const float*)d_in[9];
  const float* Wf = (const float*)d_in[10];
  const float* bf = (const float*)d_in[11];
  const float* gamma = (const float*)d_in[12];
  const float* beta = (const float*)d_in[13];

  float* out0 = (float*)d_out;               // (B,1,H)
  float* attnOut = out0 + BB * HH;           // (B*NH,1,L)

  char* ws = (char*)d_ws;
  float* qT = (float*)(ws);                  // 1 MB
  float* qkT = (float*)(ws + (1 << 20));     // 16 MB
  float* vbar = (float*)(ws + (17 << 20));   // 16 MB
  float* ctx = (float*)(ws + (33 << 20));    // 1 MB
  float* xws = (float*)(ws + (34 << 20));    // 1 MB

  k1_qproj<<<dim3(64, 16), 256, 0, stream>>>(query, Wq, bq, qT);
  k2_qk<<<dim3(16, 16), 256, 0, stream>>>(qT, Wk, qkT);
  k3_attn<<<dim3(256), 256, 0, stream>>>(key, value, mask, qkT, attnOut, vbar);
  k4_ctx<<<dim3(64, 16), 256, 0, stream>>>(vbar, Wv, bv, ctx);
  k5_outproj<<<dim3(64, 16), 256, 0, stream>>>(ctx, Wf, bf, query, xws);
  k6_ln<<<dim3(256), 256, 0, stream>>>(xws, gamma, beta, out0);
}

// Round 2
// 652.279 us; speedup vs baseline: 1.3270x; 1.3270x over previous
//
#include <hip/hip_runtime.h>
#include <math.h>

#define BB 256
#define LL 256
#define HH 1024
#define NH 16
#define DD 64
#define SCALE 0.5f
#define LN_EPS 1e-5f
#define NEG_BIG (-3.402823466e38f)

// ---------------------------------------------------------------------------
// K1: qT[j][b] = sum_i query[b][i]*Wq[j][i] + bq[j]   (transposed for K2's
// scalar loads).  grid (64,16), block 256 = 16 b x 16 j.
// ---------------------------------------------------------------------------
__global__ __launch_bounds__(256) void k1_qproj(const float* __restrict__ query,
                                                const float* __restrict__ Wq,
                                                const float* __restrict__ bq,
                                                float* __restrict__ qT) {
  const int b = (blockIdx.y << 4) + (threadIdx.x & 15);
  const int j = (blockIdx.x << 4) + (threadIdx.x >> 4);
  const float4* q4 = (const float4*)(query + (size_t)b * HH);
  const float4* w4 = (const float4*)(Wq + (size_t)j * HH);
  float acc = 0.f;
#pragma unroll 8
  for (int i = 0; i < HH / 4; i++) {
    float4 a = q4[i], w = w4[i];
    acc += a.x * w.x + a.y * w.y + a.z * w.z + a.w * w.w;
  }
  qT[j * BB + b] = acc + bq[j];
}

// ---------------------------------------------------------------------------
// K2: qkT[b][i>>2][h][i&3] = SCALE * sum_d qT[h*64+d][b] * Wk[h*64+d][i]
// grid (16 itile, 16 h, 4 bq), block 256 = 64 i x 4 b-sub; thread: 16 b's.
// 1024 blocks -> ~16 waves/CU (was 256 blocks, 1/CU).
// ---------------------------------------------------------------------------
__global__ __launch_bounds__(256) void k2_qk(const float* __restrict__ qT,
                                             const float* __restrict__ Wk,
                                             float* __restrict__ qkT) {
  const int h = blockIdx.y;
  const int it = blockIdx.x;
  const int il = threadIdx.x & 63;
  const int bs = __builtin_amdgcn_readfirstlane(threadIdx.x >> 6);
  const int i = it * 64 + il;
  const int boff = blockIdx.z * 64 + bs * 16;
  float acc[16];
#pragma unroll
  for (int k = 0; k < 16; k++) acc[k] = 0.f;
#pragma unroll 2
  for (int d = 0; d < DD; d++) {
    float wv = Wk[(size_t)(h * DD + d) * HH + i];
    const float* qrow = qT + (h * DD + d) * BB + boff;  // wave-uniform
#pragma unroll
    for (int k = 0; k < 16; k++) acc[k] = fmaf(qrow[k], wv, acc[k]);
  }
  const int gu = i >> 2, i3 = i & 3;
#pragma unroll
  for (int k = 0; k < 16; k++)
    qkT[(size_t)(boff + k) * 16384 + gu * 64 + h * 4 + i3] = SCALE * acc[k];
}

// ---------------------------------------------------------------------------
// K3a: scores[b][h][l] = mask ? NEG_BIG : sum_i key[b][l][i]*qk[b][i][h]
// (SCALE already folded into qkT).  Output layout [(b*16+h)*256+l] == the
// final attnOut layout; written into d_out's attn region, softmaxed in-place
// by K3b.
// grid (4 lt, 256 b) = 1024 blocks, block 256 = 4 waves.
// Wave g owns dim-quarter (16 dims per 64-dim tile) for all 64 rows; key tile
// staged in wave-PRIVATE LDS (row stride 20 floats: (5r+u)%8 covers all 8
// quad-banks -> b128 floor, no conflicts), double-buffered, NO barriers in
// main loop (same-wave ds ordering).  qk reads are wave-uniform -> s_load.
// Epilogue: cross-wave reduce via padded LDS (aliased over tile bufs).
// ---------------------------------------------------------------------------
__global__ __launch_bounds__(256, 4) void k3a_scores(
    const float* __restrict__ key, const int* __restrict__ mask,
    const float* __restrict__ qkT, float* __restrict__ scoresT) {
  __shared__ float smem[10240];  // 4 waves x 2 bufs x 64 rows x 20 floats
  const int b = blockIdx.y;
  const int lt = blockIdx.x;
  const int t = threadIdx.x;
  const int g = __builtin_amdgcn_readfirstlane(t >> 6);
  const int lam = t & 63;
  float* kw = smem + g * 2560;
  const float* keyb = key + ((size_t)b * LL + lt * 64) * HH;
  const float* qkb = qkT + (size_t)b * 16384;

  const int srow = lam >> 2;  // staging row base (+j*16)
  const int sc = lam & 3;     // staging 16B-unit within the wave's 16 dims

  float acc[16];
#pragma unroll
  for (int h = 0; h < NH; h++) acc[h] = 0.f;

  float4 pf[4];
#pragma unroll
  for (int j = 0; j < 4; j++)
    pf[j] = *(const float4*)(keyb + (size_t)(j * 16 + srow) * HH + g * 16 + sc * 4);

  int buf = 0;
  for (int T = 0; T < 16; T++) {
    float* kb = kw + buf * 1280;
#pragma unroll
    for (int j = 0; j < 4; j++)
      *(float4*)(kb + ((j * 16 + srow) * 5 + sc) * 4) = pf[j];
    if (T < 15) {
      const int off = (T + 1) * 64 + g * 16 + sc * 4;
#pragma unroll
      for (int j = 0; j < 4; j++)
        pf[j] = *(const float4*)(keyb + (size_t)(j * 16 + srow) * HH + off);
    }
    const float* qc = qkb + (T * 16 + g * 4) * 64;  // wave-uniform -> s_load
#pragma unroll
    for (int u = 0; u < 4; u++) {
      float4 kv = *(const float4*)(kb + (lam * 5 + u) * 4);
      const float* qu = qc + u * 64;
#pragma unroll
      for (int h = 0; h < NH; h++) {
        acc[h] = fmaf(kv.x, qu[h * 4 + 0], acc[h]);
        acc[h] = fmaf(kv.y, qu[h * 4 + 1], acc[h]);
        acc[h] = fmaf(kv.z, qu[h * 4 + 2], acc[h]);
        acc[h] = fmaf(kv.w, qu[h * 4 + 3], acc[h]);
      }
    }
    buf ^= 1;
  }

  // cross-wave reduce: part[g][row][h], rows padded to 20 floats
  __syncthreads();
  float* part = smem;
#pragma unroll
  for (int u = 0; u < 4; u++)
    *(float4*)(part + (g * 64 + lam) * 20 + u * 4) =
        make_float4(acc[u * 4], acc[u * 4 + 1], acc[u * 4 + 2], acc[u * 4 + 3]);
  __syncthreads();
  const int row = t & 63, hq = t >> 6;
  float4 s0 = *(const float4*)(part + (0 * 64 + row) * 20 + hq * 4);
  float4 s1 = *(const float4*)(part + (1 * 64 + row) * 20 + hq * 4);
  float4 s2 = *(const float4*)(part + (2 * 64 + row) * 20 + hq * 4);
  float4 s3 = *(const float4*)(part + (3 * 64 + row) * 20 + hq * 4);
  const int l = lt * 64 + row;
  const int mk = mask[b * LL + l];
  float o0 = mk ? NEG_BIG : (s0.x + s1.x + s2.x + s3.x);
  float o1 = mk ? NEG_BIG : (s0.y + s1.y + s2.y + s3.y);
  float o2 = mk ? NEG_BIG : (s0.z + s1.z + s2.z + s3.z);
  float o3 = mk ? NEG_BIG : (s0.w + s1.w + s2.w + s3.w);
  scoresT[(size_t)(b * NH + hq * 4 + 0) * LL + l] = o0;
  scoresT[(size_t)(b * NH + hq * 4 + 1) * LL + l] = o1;
  scoresT[(size_t)(b * NH + hq * 4 + 2) * LL + l] = o2;
  scoresT[(size_t)(b * NH + hq * 4 + 3) * LL + l] = o3;
}

// ---------------------------------------------------------------------------
// K3b: in-place softmax over the last dim of attn[(b*16+h)][256].
// grid 1024 blocks x 256 = wave per (b,h) row.
// ---------------------------------------------------------------------------
__global__ __launch_bounds__(256) void k3b_softmax(float* __restrict__ attn) {
  const int r = blockIdx.x * 4 + (threadIdx.x >> 6);
  const int lane = threadIdx.x & 63;
  float* rowp = attn + (size_t)r * LL;
  float4 s = *(const float4*)(rowp + lane * 4);
  float m = fmaxf(fmaxf(s.x, s.y), fmaxf(s.z, s.w));
#pragma unroll
  for (int off = 32; off >= 1; off >>= 1) m = fmaxf(m, __shfl_xor(m, off));
  float ex = __expf(s.x - m), ey = __expf(s.y - m), ez = __expf(s.z - m),
        ew = __expf(s.w - m);
  float e = ex + ey + ez + ew;
#pragma unroll
  for (int off = 32; off >= 1; off >>= 1) e += __shfl_xor(e, off);
  float inv = 1.0f / e;
  float4 o = make_float4(ex * inv, ey * inv, ez * inv, ew * inv);
  *(float4*)(rowp + lane * 4) = o;
}

// ---------------------------------------------------------------------------
// K3c: vbar[b][h][d] = sum_l attn[b][h][l] * value[b][l][d]
// grid (4 dq, 256 b) = 1024 blocks, block 256; thread owns one d.
// attn[b] staged linearly in LDS [h][l] (16KB); reads are wave-uniform b128
// broadcasts.  value stream fully coalesced (lanes = consecutive d).
// ---------------------------------------------------------------------------
__global__ __launch_bounds__(256, 4) void k3c_vbar(
    const float* __restrict__ value, const float* __restrict__ attn,
    float* __restrict__ vbar) {
  __shared__ float att[4096];  // [h][l]
  const int b = blockIdx.y;
  const int t = threadIdx.x;
  const float* ab = attn + (size_t)b * NH * LL;
#pragma unroll
  for (int j = 0; j < 4; j++)
    *(float4*)(att + j * 1024 + t * 4) = *(const float4*)(ab + j * 1024 + t * 4);
  __syncthreads();
  const int d = blockIdx.x * 256 + t;
  const float* valb = value + (size_t)b * LL * HH + d;
  float acc[16];
#pragma unroll
  for (int h = 0; h < NH; h++) acc[h] = 0.f;
#pragma unroll 2
  for (int l0 = 0; l0 < LL; l0 += 4) {
    float v0 = valb[(size_t)(l0 + 0) * HH];
    float v1 = valb[(size_t)(l0 + 1) * HH];
    float v2 = valb[(size_t)(l0 + 2) * HH];
    float v3 = valb[(size_t)(l0 + 3) * HH];
#pragma unroll
    for (int h = 0; h < NH; h++) {
      float4 a = *(const float4*)(att + h * LL + l0);  // uniform broadcast
      acc[h] = fmaf(a.x, v0, acc[h]);
      acc[h] = fmaf(a.y, v1, acc[h]);
      acc[h] = fmaf(a.z, v2, acc[h]);
      acc[h] = fmaf(a.w, v3, acc[h]);
    }
  }
#pragma unroll
  for (int h = 0; h < NH; h++) vbar[((size_t)b * NH + h) * HH + d] = acc[h];
}

// ---------------------------------------------------------------------------
// K4: ctx[b][j] = sum_i vbar[b][j>>6][i] * Wv[j][i] + bv[j]
// ---------------------------------------------------------------------------
__global__ __launch_bounds__(256) void k4_ctx(const float* __restrict__ vbar,
                                              const float* __restrict__ Wv,
                                              const float* __restrict__ bv,
                                              float* __restrict__ ctx) {
  const int b = (blockIdx.y << 4) + (threadIdx.x & 15);
  const int j = (blockIdx.x << 4) + (threadIdx.x >> 4);
  const float4* a4 = (const float4*)(vbar + (size_t)b * 16384 + (j >> 6) * HH);
  const float4* w4 = (const float4*)(Wv + (size_t)j * HH);
  float acc = 0.f;
#pragma unroll 8
  for (int i = 0; i < HH / 4; i++) {
    float4 a = a4[i], w = w4[i];
    acc += a.x * w.x + a.y * w.y + a.z * w.z + a.w * w.w;
  }
  ctx[b * HH + j] = acc + bv[j];
}

// ---------------------------------------------------------------------------
// K5: x[b][j] = query[b][j] + sum_i ctx[b][i]*Wf[j][i] + bf[j]
// ---------------------------------------------------------------------------
__global__ __launch_bounds__(256) void k5_outproj(const float* __restrict__ ctx,
                                                  const float* __restrict__ Wf,
                                                  const float* __restrict__ bf,
                                                  const float* __restrict__ query,
                                                  float* __restrict__ xws) {
  const int b = (blockIdx.y << 4) + (threadIdx.x & 15);
  const int j = (blockIdx.x << 4) + (threadIdx.x >> 4);
  const float4* a4 = (const float4*)(ctx + (size_t)b * HH);
  const float4* w4 = (const float4*)(Wf + (size_t)j * HH);
  float acc = 0.f;
#pragma unroll 8
  for (int i = 0; i < HH / 4; i++) {
    float4 a = a4[i], w = w4[i];
    acc += a.x * w.x + a.y * w.y + a.z * w.z + a.w * w.w;
  }
  xws[b * HH + j] = acc + bf[j] + query[(size_t)b * HH + j];
}

// ---------------------------------------------------------------------------
// K6: LayerNorm over H, two-pass (exact), block per b.
// ---------------------------------------------------------------------------
__global__ __launch_bounds__(256) void k6_ln(const float* __restrict__ xws,
                                             const float* __restrict__ gamma,
                                             const float* __restrict__ beta,
                                             float* __restrict__ out0) {
  __shared__ float rb[8];
  const int b = blockIdx.x, t = threadIdx.x;
  float4 v = *(const float4*)(xws + (size_t)b * HH + 4 * t);
  float s = v.x + v.y + v.z + v.w;
#pragma unroll
  for (int off = 32; off >= 1; off >>= 1) s += __shfl_xor(s, off);
  if ((t & 63) == 0) rb[t >> 6] = s;
  __syncthreads();
  float mu = (rb[0] + rb[1] + rb[2] + rb[3]) * (1.0f / HH);
  float dx = v.x - mu, dy = v.y - mu, dz = v.z - mu, dw = v.w - mu;
  float q = dx * dx + dy * dy + dz * dz + dw * dw;
#pragma unroll
  for (int off = 32; off >= 1; off >>= 1) q += __shfl_xor(q, off);
  if ((t & 63) == 0) rb[4 + (t >> 6)] = q;
  __syncthreads();
  float var = (rb[4] + rb[5] + rb[6] + rb[7]) * (1.0f / HH);
  float rs = rsqrtf(var + LN_EPS);
  float4 gm = *(const float4*)(gamma + 4 * t);
  float4 bt = *(const float4*)(beta + 4 * t);
  float4 o;
  o.x = dx * rs * gm.x + bt.x;
  o.y = dy * rs * gm.y + bt.y;
  o.z = dz * rs * gm.z + bt.z;
  o.w = dw * rs * gm.w + bt.w;
  *(float4*)(out0 + (size_t)b * HH + 4 * t) = o;
}

extern "C" void kernel_launch(void* const* d_in, const int* in_sizes, int n_in,
                              void* d_out, int out_size, void* d_ws,
                              size_t ws_size, hipStream_t stream) {
  (void)in_sizes; (void)n_in; (void)out_size; (void)ws_size;
  const float* key = (const float*)d_in[0];
  const float* value = (const float*)d_in[1];
  const float* query = (const float*)d_in[2];
  const int* mask = (const int*)d_in[3];
  const float* Wq = (const float*)d_in[4];
  const float* bq = (const float*)d_in[5];
  const float* Wk = (const float*)d_in[6];
  // d_in[7] = bk: constant per (b,h) score shift -> softmax-invariant, dropped
  const float* Wv = (const float*)d_in[8];
  const float* bv = (const float*)d_in[9];
  const float* Wf = (const float*)d_in[10];
  const float* bf = (const float*)d_in[11];
  const float* gamma = (const float*)d_in[12];
  const float* beta = (const float*)d_in[13];

  float* out0 = (float*)d_out;      // (B,1,H)
  float* attnOut = out0 + BB * HH;  // (B*NH,1,L) — scores written here, then
                                    // softmaxed in place by k3b

  char* ws = (char*)d_ws;
  float* qT = (float*)(ws);                 // 1 MB
  float* qkT = (float*)(ws + (1 << 20));    // 16 MB
  float* vbar = (float*)(ws + (17 << 20));  // 16 MB
  float* ctx = (float*)(ws + (33 << 20));   // 1 MB
  float* xws = (float*)(ws + (34 << 20));   // 1 MB

  k1_qproj<<<dim3(64, 16), 256, 0, stream>>>(query, Wq, bq, qT);
  k2_qk<<<dim3(16, 16, 4), 256, 0, stream>>>(qT, Wk, qkT);
  k3a_scores<<<dim3(4, 256), 256, 0, stream>>>(key, mask, qkT, attnOut);
  k3b_softmax<<<dim3(1024), 256, 0, stream>>>(attnOut);
  k3c_vbar<<<dim3(4, 256), 256, 0, stream>>>(value, attnOut, vbar);
  k4_ctx<<<dim3(64, 16), 256, 0, stream>>>(vbar, Wv, bv, ctx);
  k5_outproj<<<dim3(64, 16), 256, 0, stream>>>(ctx, Wf, bf, query, xws);
  k6_ln<<<dim3(256), 256, 0, stream>>>(xws, gamma, beta, out0);
}

// Round 3
// 430.904 us; speedup vs baseline: 2.0087x; 1.5137x over previous
//
#include <hip/hip_runtime.h>
#include <math.h>

#define BB 256
#define LL 256
#define HH 1024
#define NH 16
#define DD 64
#define SCALE 0.5f
#define LN_EPS 1e-5f
#define NEG_BIG (-3.402823466e38f)

// ---------------------------------------------------------------------------
// t_tr: tiled 64x64 transpose with strides, z-planes for 3D permutes.
// out[plane z][c][r] = in[plane z][r][c].  Coalesced both sides via LDS.
// grid (C/64, R/64, Z), block 256.
// ---------------------------------------------------------------------------
__global__ __launch_bounds__(256) void t_tr(const float* __restrict__ in,
                                            float* __restrict__ out, int inRS,
                                            int outRS, int inPlane,
                                            int outPlane) {
  __shared__ float lds[64][68];  // 68: keeps float4 alignment, 8-bank spread
  const float* ip = in + (size_t)blockIdx.z * inPlane;
  float* op = out + (size_t)blockIdx.z * outPlane;
  const int rt = blockIdx.y, ct = blockIdx.x;
  const int lr = threadIdx.x >> 4;        // 0..15
  const int lc = (threadIdx.x & 15) * 4;  // 0..60
#pragma unroll
  for (int p = 0; p < 4; p++) {
    float4 v = *(const float4*)(ip + (size_t)(rt * 64 + p * 16 + lr) * inRS +
                                ct * 64 + lc);
    *(float4*)(&lds[p * 16 + lr][lc]) = v;
  }
  __syncthreads();
#pragma unroll
  for (int p = 0; p < 4; p++) {
    float4 v = make_float4(lds[lc + 0][p * 16 + lr], lds[lc + 1][p * 16 + lr],
                           lds[lc + 2][p * 16 + lr], lds[lc + 3][p * 16 + lr]);
    *(float4*)(op + (size_t)(ct * 64 + p * 16 + lr) * outRS + rt * 64 + lc) = v;
  }
}

// ---------------------------------------------------------------------------
// K1: qT[j][b] = bq[j] + sum_i query[b][i]*Wq[j][i]
// k3a-style: lane = j (64 rows/tile), 4 waves own i-quarters (16 i per 64-i
// chunk), Wq tile staged in wave-private padded LDS (coalesced 4 lanes/row),
// uniform operand qTT[i][b] via s_load (8 b's), acc[8], LDS cross-wave
// reduce.  grid (16 j-tiles, 32 b-groups) = 512 blocks.
// ---------------------------------------------------------------------------
__global__ __launch_bounds__(256) void k1_qproj(const float* __restrict__ Wq,
                                                const float* __restrict__ qTT,
                                                const float* __restrict__ bq,
                                                float* __restrict__ qT) {
  __shared__ float smem[10240];
  const int jt = blockIdx.x;
  const int boff = blockIdx.y * 8;
  const int t = threadIdx.x;
  const int g = __builtin_amdgcn_readfirstlane(t >> 6);
  const int ln = t & 63;
  float* kw = smem + g * 2560;
  const float* Wb = Wq + (size_t)(jt * 64) * HH;
  const int srow = ln >> 2, sc = ln & 3;

  float acc[8];
#pragma unroll
  for (int c = 0; c < 8; c++) acc[c] = 0.f;
  float4 pf[4];
#pragma unroll
  for (int p = 0; p < 4; p++)
    pf[p] = *(const float4*)(Wb + (size_t)(p * 16 + srow) * HH + g * 16 + sc * 4);
  int buf = 0;
  for (int T = 0; T < 16; T++) {
    float* kb = kw + buf * 1280;
#pragma unroll
    for (int p = 0; p < 4; p++)
      *(float4*)(kb + ((p * 16 + srow) * 5 + sc) * 4) = pf[p];
    if (T < 15) {
      const int off = (T + 1) * 64 + g * 16 + sc * 4;
#pragma unroll
      for (int p = 0; p < 4; p++)
        pf[p] = *(const float4*)(Wb + (size_t)(p * 16 + srow) * HH + off);
    }
    const int i0 = T * 64 + g * 16;
#pragma unroll
    for (int u = 0; u < 4; u++) {
      float4 kv = *(const float4*)(kb + (ln * 5 + u) * 4);
      const float* q0 = qTT + (size_t)(i0 + u * 4 + 0) * BB + boff;
      const float* q1 = qTT + (size_t)(i0 + u * 4 + 1) * BB + boff;
      const float* q2 = qTT + (size_t)(i0 + u * 4 + 2) * BB + boff;
      const float* q3 = qTT + (size_t)(i0 + u * 4 + 3) * BB + boff;
#pragma unroll
      for (int c = 0; c < 8; c++) {
        acc[c] = fmaf(kv.x, q0[c], acc[c]);
        acc[c] = fmaf(kv.y, q1[c], acc[c]);
        acc[c] = fmaf(kv.z, q2[c], acc[c]);
        acc[c] = fmaf(kv.w, q3[c], acc[c]);
      }
    }
    buf ^= 1;
  }
  __syncthreads();
  float* part = smem;
  *(float4*)(part + g * 768 + ln * 12 + 0) =
      make_float4(acc[0], acc[1], acc[2], acc[3]);
  *(float4*)(part + g * 768 + ln * 12 + 4) =
      make_float4(acc[4], acc[5], acc[6], acc[7]);
  __syncthreads();
  const int j = t & 63, c0 = (t >> 6) * 2;
  float v0 = 0.f, v1 = 0.f;
#pragma unroll
  for (int g2 = 0; g2 < 4; g2++) {
    v0 += part[g2 * 768 + j * 12 + c0];
    v1 += part[g2 * 768 + j * 12 + c0 + 1];
  }
  const int jg = jt * 64 + j;
  const float bias = bq[jg];
  *(float2*)(qT + (size_t)jg * BB + boff + c0) =
      make_float2(v0 + bias, v1 + bias);
}

// ---------------------------------------------------------------------------
// K2: qkT[b][h][i] = SCALE * sum_d qT[h*64+d][b] * Wk[h*64+d][i]
// grid (16 itile, 16 h, 4 bq), block 256.  Coalesced loads and stores;
// qrow wave-uniform s_load.
// ---------------------------------------------------------------------------
__global__ __launch_bounds__(256) void k2_qk(const float* __restrict__ qT,
                                             const float* __restrict__ Wk,
                                             float* __restrict__ qkT) {
  const int h = blockIdx.y;
  const int it = blockIdx.x;
  const int il = threadIdx.x & 63;
  const int bs = __builtin_amdgcn_readfirstlane(threadIdx.x >> 6);
  const int i = it * 64 + il;
  const int boff = blockIdx.z * 64 + bs * 16;
  float acc[16];
#pragma unroll
  for (int k = 0; k < 16; k++) acc[k] = 0.f;
#pragma unroll 2
  for (int d = 0; d < DD; d++) {
    float wv = Wk[(size_t)(h * DD + d) * HH + i];
    const float* qrow = qT + (h * DD + d) * BB + boff;  // wave-uniform
#pragma unroll
    for (int k = 0; k < 16; k++) acc[k] = fmaf(qrow[k], wv, acc[k]);
  }
#pragma unroll
  for (int k = 0; k < 16; k++)
    qkT[(size_t)((boff + k) * NH + h) * HH + i] = SCALE * acc[k];
}

// ---------------------------------------------------------------------------
// K3a: scores[b][h][l] = mask ? NEG_BIG : sum_i key[b][l][i]*qk[b][h][i]
// grid (4 lt, 256 b), block 256 = 4 waves; wave-private LDS staging (stride
// 20), qk s_loadx4 uniform operands, LDS cross-wave reduce epilogue.
// ---------------------------------------------------------------------------
__global__ __launch_bounds__(256, 4) void k3a_scores(
    const float* __restrict__ key, const int* __restrict__ mask,
    const float* __restrict__ qkT, float* __restrict__ scoresT) {
  __shared__ float smem[10240];
  const int b = blockIdx.y;
  const int lt = blockIdx.x;
  const int t = threadIdx.x;
  const int g = __builtin_amdgcn_readfirstlane(t >> 6);
  const int lam = t & 63;
  float* kw = smem + g * 2560;
  const float* keyb = key + ((size_t)b * LL + lt * 64) * HH;
  const float* qkb = qkT + (size_t)b * (NH * HH);  // [16 h][1024]

  const int srow = lam >> 2;
  const int sc = lam & 3;

  float acc[16];
#pragma unroll
  for (int h = 0; h < NH; h++) acc[h] = 0.f;

  float4 pf[4];
#pragma unroll
  for (int j = 0; j < 4; j++)
    pf[j] = *(const float4*)(keyb + (size_t)(j * 16 + srow) * HH + g * 16 + sc * 4);

  int buf = 0;
  for (int T = 0; T < 16; T++) {
    float* kb = kw + buf * 1280;
#pragma unroll
    for (int j = 0; j < 4; j++)
      *(float4*)(kb + ((j * 16 + srow) * 5 + sc) * 4) = pf[j];
    if (T < 15) {
      const int off = (T + 1) * 64 + g * 16 + sc * 4;
#pragma unroll
      for (int j = 0; j < 4; j++)
        pf[j] = *(const float4*)(keyb + (size_t)(j * 16 + srow) * HH + off);
    }
    const int i0 = T * 64 + g * 16;
#pragma unroll
    for (int u = 0; u < 4; u++) {
      float4 kv = *(const float4*)(kb + (lam * 5 + u) * 4);
      const int ib = i0 + u * 4;
#pragma unroll
      for (int h = 0; h < NH; h++) {
        const float* qh = qkb + h * HH + ib;  // wave-uniform -> s_load
        acc[h] = fmaf(kv.x, qh[0], acc[h]);
        acc[h] = fmaf(kv.y, qh[1], acc[h]);
        acc[h] = fmaf(kv.z, qh[2], acc[h]);
        acc[h] = fmaf(kv.w, qh[3], acc[h]);
      }
    }
    buf ^= 1;
  }

  __syncthreads();
  float* part = smem;
#pragma unroll
  for (int u = 0; u < 4; u++)
    *(float4*)(part + (g * 64 + lam) * 20 + u * 4) =
        make_float4(acc[u * 4], acc[u * 4 + 1], acc[u * 4 + 2], acc[u * 4 + 3]);
  __syncthreads();
  const int row = t & 63, hq = t >> 6;
  float4 s0 = *(const float4*)(part + (0 * 64 + row) * 20 + hq * 4);
  float4 s1 = *(const float4*)(part + (1 * 64 + row) * 20 + hq * 4);
  float4 s2 = *(const float4*)(part + (2 * 64 + row) * 20 + hq * 4);
  float4 s3 = *(const float4*)(part + (3 * 64 + row) * 20 + hq * 4);
  const int l = lt * 64 + row;
  const int mk = mask[b * LL + l];
  float o0 = mk ? NEG_BIG : (s0.x + s1.x + s2.x + s3.x);
  float o1 = mk ? NEG_BIG : (s0.y + s1.y + s2.y + s3.y);
  float o2 = mk ? NEG_BIG : (s0.z + s1.z + s2.z + s3.z);
  float o3 = mk ? NEG_BIG : (s0.w + s1.w + s2.w + s3.w);
  scoresT[(size_t)(b * NH + hq * 4 + 0) * LL + l] = o0;
  scoresT[(size_t)(b * NH + hq * 4 + 1) * LL + l] = o1;
  scoresT[(size_t)(b * NH + hq * 4 + 2) * LL + l] = o2;
  scoresT[(size_t)(b * NH + hq * 4 + 3) * LL + l] = o3;
}

// ---------------------------------------------------------------------------
// K3b: in-place softmax over the last dim of attn[(b*16+h)][256].
// ---------------------------------------------------------------------------
__global__ __launch_bounds__(256) void k3b_softmax(float* __restrict__ attn) {
  const int r = blockIdx.x * 4 + (threadIdx.x >> 6);
  const int lane = threadIdx.x & 63;
  float* rowp = attn + (size_t)r * LL;
  float4 s = *(const float4*)(rowp + lane * 4);
  float m = fmaxf(fmaxf(s.x, s.y), fmaxf(s.z, s.w));
#pragma unroll
  for (int off = 32; off >= 1; off >>= 1) m = fmaxf(m, __shfl_xor(m, off));
  float ex = __expf(s.x - m), ey = __expf(s.y - m), ez = __expf(s.z - m),
        ew = __expf(s.w - m);
  float e = ex + ey + ez + ew;
#pragma unroll
  for (int off = 32; off >= 1; off >>= 1) e += __shfl_xor(e, off);
  float inv = 1.0f / e;
  *(float4*)(rowp + lane * 4) = make_float4(ex * inv, ey * inv, ez * inv, ew * inv);
}

// ---------------------------------------------------------------------------
// K3c: vbar[b][h][d] = sum_l attn[b][h][l] * value[b][l][d]
// grid (4 dq, 256 b), block 256, thread owns one d.  NO LDS: attn rows read
// as wave-uniform 16-float chunks (s_load), value in 16-deep coalesced
// dword bursts.
// ---------------------------------------------------------------------------
__global__ __launch_bounds__(256, 4) void k3c_vbar(
    const float* __restrict__ value, const float* __restrict__ attn,
    float* __restrict__ vbar) {
  const int b = blockIdx.y;
  const int d = blockIdx.x * 256 + threadIdx.x;
  const float* ab = attn + (size_t)b * NH * LL;
  const float* valb = value + (size_t)b * LL * HH + d;
  float acc[16];
#pragma unroll
  for (int h = 0; h < NH; h++) acc[h] = 0.f;
  for (int l0 = 0; l0 < LL; l0 += 16) {
    float vv[16];
#pragma unroll
    for (int k = 0; k < 16; k++) vv[k] = valb[(size_t)(l0 + k) * HH];
#pragma unroll
    for (int h = 0; h < NH; h++) {
      const float4* ar = (const float4*)(ab + h * LL + l0);  // uniform
      float4 a0 = ar[0], a1 = ar[1], a2 = ar[2], a3 = ar[3];
      acc[h] = fmaf(a0.x, vv[0], acc[h]);
      acc[h] = fmaf(a0.y, vv[1], acc[h]);
      acc[h] = fmaf(a0.z, vv[2], acc[h]);
      acc[h] = fmaf(a0.w, vv[3], acc[h]);
      acc[h] = fmaf(a1.x, vv[4], acc[h]);
      acc[h] = fmaf(a1.y, vv[5], acc[h]);
      acc[h] = fmaf(a1.z, vv[6], acc[h]);
      acc[h] = fmaf(a1.w, vv[7], acc[h]);
      acc[h] = fmaf(a2.x, vv[8], acc[h]);
      acc[h] = fmaf(a2.y, vv[9], acc[h]);
      acc[h] = fmaf(a2.z, vv[10], acc[h]);
      acc[h] = fmaf(a2.w, vv[11], acc[h]);
      acc[h] = fmaf(a3.x, vv[12], acc[h]);
      acc[h] = fmaf(a3.y, vv[13], acc[h]);
      acc[h] = fmaf(a3.z, vv[14], acc[h]);
      acc[h] = fmaf(a3.w, vv[15], acc[h]);
    }
  }
#pragma unroll
  for (int h = 0; h < NH; h++)
    vbar[((size_t)b * NH + h) * HH + d] = acc[h];
}

// ---------------------------------------------------------------------------
// K4: ctxT[j][b] = bv[j] + sum_i vbar[b][jt][i] * Wv[j][i]   (jt = j>>6)
// k3a-style clone of K1; uniform operand vbarT[(h*1024+i)][b].
// grid (16 j-tiles, 32 b-groups).
// ---------------------------------------------------------------------------
__global__ __launch_bounds__(256) void k4_ctx(const float* __restrict__ Wv,
                                              const float* __restrict__ vbarT,
                                              const float* __restrict__ bv,
                                              float* __restrict__ ctxT) {
  __shared__ float smem[10240];
  const int jt = blockIdx.x;
  const int boff = blockIdx.y * 8;
  const int t = threadIdx.x;
  const int g = __builtin_amdgcn_readfirstlane(t >> 6);
  const int ln = t & 63;
  float* kw = smem + g * 2560;
  const float* Wb = Wv + (size_t)(jt * 64) * HH;
  const float* vt = vbarT + (size_t)jt * HH * BB;  // head jt's [1024 i][256 b]
  const int srow = ln >> 2, sc = ln & 3;

  float acc[8];
#pragma unroll
  for (int c = 0; c < 8; c++) acc[c] = 0.f;
  float4 pf[4];
#pragma unroll
  for (int p = 0; p < 4; p++)
    pf[p] = *(const float4*)(Wb + (size_t)(p * 16 + srow) * HH + g * 16 + sc * 4);
  int buf = 0;
  for (int T = 0; T < 16; T++) {
    float* kb = kw + buf * 1280;
#pragma unroll
    for (int p = 0; p < 4; p++)
      *(float4*)(kb + ((p * 16 + srow) * 5 + sc) * 4) = pf[p];
    if (T < 15) {
      const int off = (T + 1) * 64 + g * 16 + sc * 4;
#pragma unroll
      for (int p = 0; p < 4; p++)
        pf[p] = *(const float4*)(Wb + (size_t)(p * 16 + srow) * HH + off);
    }
    const int i0 = T * 64 + g * 16;
#pragma unroll
    for (int u = 0; u < 4; u++) {
      float4 kv = *(const float4*)(kb + (ln * 5 + u) * 4);
      const float* q0 = vt + (size_t)(i0 + u * 4 + 0) * BB + boff;
      const float* q1 = vt + (size_t)(i0 + u * 4 + 1) * BB + boff;
      const float* q2 = vt + (size_t)(i0 + u * 4 + 2) * BB + boff;
      const float* q3 = vt + (size_t)(i0 + u * 4 + 3) * BB + boff;
#pragma unroll
      for (int c = 0; c < 8; c++) {
        acc[c] = fmaf(kv.x, q0[c], acc[c]);
        acc[c] = fmaf(kv.y, q1[c], acc[c]);
        acc[c] = fmaf(kv.z, q2[c], acc[c]);
        acc[c] = fmaf(kv.w, q3[c], acc[c]);
      }
    }
    buf ^= 1;
  }
  __syncthreads();
  float* part = smem;
  *(float4*)(part + g * 768 + ln * 12 + 0) =
      make_float4(acc[0], acc[1], acc[2], acc[3]);
  *(float4*)(part + g * 768 + ln * 12 + 4) =
      make_float4(acc[4], acc[5], acc[6], acc[7]);
  __syncthreads();
  const int j = t & 63, c0 = (t >> 6) * 2;
  float v0 = 0.f, v1 = 0.f;
#pragma unroll
  for (int g2 = 0; g2 < 4; g2++) {
    v0 += part[g2 * 768 + j * 12 + c0];
    v1 += part[g2 * 768 + j * 12 + c0 + 1];
  }
  const int jg = jt * 64 + j;
  const float bias = bv[jg];
  *(float2*)(ctxT + (size_t)jg * BB + boff + c0) =
      make_float2(v0 + bias, v1 + bias);
}

// ---------------------------------------------------------------------------
// K5: xws[b][j] = query[b][j] + bf[j] + sum_i ctxT[i][b] * Wf[j][i]
// k3a-style clone; epilogue adds residual + bias, stores row-major.
// ---------------------------------------------------------------------------
__global__ __launch_bounds__(256) void k5_outproj(
    const float* __restrict__ Wf, const float* __restrict__ ctxT,
    const float* __restrict__ bf, const float* __restrict__ query,
    float* __restrict__ xws) {
  __shared__ float smem[10240];
  const int jt = blockIdx.x;
  const int boff = blockIdx.y * 8;
  const int t = threadIdx.x;
  const int g = __builtin_amdgcn_readfirstlane(t >> 6);
  const int ln = t & 63;
  float* kw = smem + g * 2560;
  const float* Wb = Wf + (size_t)(jt * 64) * HH;
  const int srow = ln >> 2, sc = ln & 3;

  float acc[8];
#pragma unroll
  for (int c = 0; c < 8; c++) acc[c] = 0.f;
  float4 pf[4];
#pragma unroll
  for (int p = 0; p < 4; p++)
    pf[p] = *(const float4*)(Wb + (size_t)(p * 16 + srow) * HH + g * 16 + sc * 4);
  int buf = 0;
  for (int T = 0; T < 16; T++) {
    float* kb = kw + buf * 1280;
#pragma unroll
    for (int p = 0; p < 4; p++)
      *(float4*)(kb + ((p * 16 + srow) * 5 + sc) * 4) = pf[p];
    if (T < 15) {
      const int off = (T + 1) * 64 + g * 16 + sc * 4;
#pragma unroll
      for (int p = 0; p < 4; p++)
        pf[p] = *(const float4*)(Wb + (size_t)(p * 16 + srow) * HH + off);
    }
    const int i0 = T * 64 + g * 16;
#pragma unroll
    for (int u = 0; u < 4; u++) {
      float4 kv = *(const float4*)(kb + (ln * 5 + u) * 4);
      const float* q0 = ctxT + (size_t)(i0 + u * 4 + 0) * BB + boff;
      const float* q1 = ctxT + (size_t)(i0 + u * 4 + 1) * BB + boff;
      const float* q2 = ctxT + (size_t)(i0 + u * 4 + 2) * BB + boff;
      const float* q3 = ctxT + (size_t)(i0 + u * 4 + 3) * BB + boff;
#pragma unroll
      for (int c = 0; c < 8; c++) {
        acc[c] = fmaf(kv.x, q0[c], acc[c]);
        acc[c] = fmaf(kv.y, q1[c], acc[c]);
        acc[c] = fmaf(kv.z, q2[c], acc[c]);
        acc[c] = fmaf(kv.w, q3[c], acc[c]);
      }
    }
    buf ^= 1;
  }
  __syncthreads();
  float* part = smem;
  *(float4*)(part + g * 768 + ln * 12 + 0) =
      make_float4(acc[0], acc[1], acc[2], acc[3]);
  *(float4*)(part + g * 768 + ln * 12 + 4) =
      make_float4(acc[4], acc[5], acc[6], acc[7]);
  __syncthreads();
  const int j = t & 63, c0 = (t >> 6) * 2;
  float v0 = 0.f, v1 = 0.f;
#pragma unroll
  for (int g2 = 0; g2 < 4; g2++) {
    v0 += part[g2 * 768 + j * 12 + c0];
    v1 += part[g2 * 768 + j * 12 + c0 + 1];
  }
  const int jg = jt * 64 + j;
  const float bias = bf[jg];
  const int b0 = boff + c0;
  xws[(size_t)b0 * HH + jg] = v0 + bias + query[(size_t)b0 * HH + jg];
  xws[(size_t)(b0 + 1) * HH + jg] = v1 + bias + query[(size_t)(b0 + 1) * HH + jg];
}

// ---------------------------------------------------------------------------
// K6: LayerNorm over H, two-pass (exact), block per b.
// ---------------------------------------------------------------------------
__global__ __launch_bounds__(256) void k6_ln(const float* __restrict__ xws,
                                             const float* __restrict__ gamma,
                                             const float* __restrict__ beta,
                                             float* __restrict__ out0) {
  __shared__ float rb[8];
  const int b = blockIdx.x, t = threadIdx.x;
  float4 v = *(const float4*)(xws + (size_t)b * HH + 4 * t);
  float s = v.x + v.y + v.z + v.w;
#pragma unroll
  for (int off = 32; off >= 1; off >>= 1) s += __shfl_xor(s, off);
  if ((t & 63) == 0) rb[t >> 6] = s;
  __syncthreads();
  float mu = (rb[0] + rb[1] + rb[2] + rb[3]) * (1.0f / HH);
  float dx = v.x - mu, dy = v.y - mu, dz = v.z - mu, dw = v.w - mu;
  float q = dx * dx + dy * dy + dz * dz + dw * dw;
#pragma unroll
  for (int off = 32; off >= 1; off >>= 1) q += __shfl_xor(q, off);
  if ((t & 63) == 0) rb[4 + (t >> 6)] = q;
  __syncthreads();
  float var = (rb[4] + rb[5] + rb[6] + rb[7]) * (1.0f / HH);
  float rs = rsqrtf(var + LN_EPS);
  float4 gm = *(const float4*)(gamma + 4 * t);
  float4 bt = *(const float4*)(beta + 4 * t);
  float4 o;
  o.x = dx * rs * gm.x + bt.x;
  o.y = dy * rs * gm.y + bt.y;
  o.z = dz * rs * gm.z + bt.z;
  o.w = dw * rs * gm.w + bt.w;
  *(float4*)(out0 + (size_t)b * HH + 4 * t) = o;
}

extern "C" void kernel_launch(void* const* d_in, const int* in_sizes, int n_in,
                              void* d_out, int out_size, void* d_ws,
                              size_t ws_size, hipStream_t stream) {
  (void)in_sizes; (void)n_in; (void)out_size; (void)ws_size;
  const float* key = (const float*)d_in[0];
  const float* value = (const float*)d_in[1];
  const float* query = (const float*)d_in[2];
  const int* mask = (const int*)d_in[3];
  const float* Wq = (const float*)d_in[4];
  const float* bq = (const float*)d_in[5];
  const float* Wk = (const float*)d_in[6];
  // d_in[7] = bk: constant per (b,h) score shift -> softmax-invariant, dropped
  const float* Wv = (const float*)d_in[8];
  const float* bv = (const float*)d_in[9];
  const float* Wf = (const float*)d_in[10];
  const float* bf = (const float*)d_in[11];
  const float* gamma = (const float*)d_in[12];
  const float* beta = (const float*)d_in[13];

  float* out0 = (float*)d_out;      // (B,1,H)
  float* attnOut = out0 + BB * HH;  // (B*NH,1,L): scores -> softmax in place

  char* ws = (char*)d_ws;
  float* qT = (float*)(ws);                  //  1 MB [j][b]
  float* qTT = (float*)(ws + (1 << 20));     //  1 MB [i][b]
  float* qkT = (float*)(ws + (2 << 20));     // 16 MB [b][h][i]
  float* vbar = (float*)(ws + (18 << 20));   // 16 MB [b][h][i]
  float* vbarT = (float*)(ws + (34 << 20));  // 16 MB [h][i][b]
  float* ctxT = (float*)(ws + (50 << 20));   //  1 MB [j][b]
  float* xws = (float*)(ws + (51 << 20));    //  1 MB [b][j]

  // query [256][1024] -> qTT [1024][256]
  t_tr<<<dim3(16, 4, 1), 256, 0, stream>>>(query, qTT, HH, BB, 0, 0);
  k1_qproj<<<dim3(16, 32), 256, 0, stream>>>(Wq, qTT, bq, qT);
  k2_qk<<<dim3(16, 16, 4), 256, 0, stream>>>(qT, Wk, qkT);
  k3a_scores<<<dim3(4, 256), 256, 0, stream>>>(key, mask, qkT, attnOut);
  k3b_softmax<<<dim3(1024), 256, 0, stream>>>(attnOut);
  k3c_vbar<<<dim3(4, 256), 256, 0, stream>>>(value, attnOut, vbar);
  // vbar (b,h,i) -> vbarT (h,i,b): per-h 256x1024 transpose
  t_tr<<<dim3(16, 4, 16), 256, 0, stream>>>(vbar, vbarT, NH * HH, BB, HH,
                                            HH * BB);
  k4_ctx<<<dim3(16, 32), 256, 0, stream>>>(Wv, vbarT, bv, ctxT);
  k5_outproj<<<dim3(16, 32), 256, 0, stream>>>(Wf, ctxT, bf, query, xws);
  k6_ln<<<dim3(256), 256, 0, stream>>>(xws, gamma, beta, out0);
}

// Round 5
// 358.764 us; speedup vs baseline: 2.4126x; 1.2011x over previous
//
#include <hip/hip_runtime.h>
#include <math.h>

#define BB 256
#define LL 256
#define HH 1024
#define NH 16
#define DD 64
#define SCALE 0.5f
#define LN_EPS 1e-5f
#define NEG_BIG (-3.402823466e38f)

// ---------------------------------------------------------------------------
// t_tr: tiled 64x64 transpose with strides, z-planes for 3D permutes.
// ---------------------------------------------------------------------------
__global__ __launch_bounds__(256) void t_tr(const float* __restrict__ in,
                                            float* __restrict__ out, int inRS,
                                            int outRS, int inPlane,
                                            int outPlane) {
  __shared__ float lds[64][68];
  const float* ip = in + (size_t)blockIdx.z * inPlane;
  float* op = out + (size_t)blockIdx.z * outPlane;
  const int rt = blockIdx.y, ct = blockIdx.x;
  const int lr = threadIdx.x >> 4;
  const int lc = (threadIdx.x & 15) * 4;
#pragma unroll
  for (int p = 0; p < 4; p++) {
    float4 v = *(const float4*)(ip + (size_t)(rt * 64 + p * 16 + lr) * inRS +
                                ct * 64 + lc);
    *(float4*)(&lds[p * 16 + lr][lc]) = v;
  }
  __syncthreads();
#pragma unroll
  for (int p = 0; p < 4; p++) {
    float4 v = make_float4(lds[lc + 0][p * 16 + lr], lds[lc + 1][p * 16 + lr],
                           lds[lc + 2][p * 16 + lr], lds[lc + 3][p * 16 + lr]);
    *(float4*)(op + (size_t)(ct * 64 + p * 16 + lr) * outRS + rt * 64 + lc) = v;
  }
}

// ---------------------------------------------------------------------------
// K1: qT[j][b] = bq[j] + sum_i query[b][i]*Wq[j][i]
// ---------------------------------------------------------------------------
__global__ __launch_bounds__(256) void k1_qproj(const float* __restrict__ Wq,
                                                const float* __restrict__ qTT,
                                                const float* __restrict__ bq,
                                                float* __restrict__ qT) {
  __shared__ float smem[10240];
  const int jt = blockIdx.x;
  const int boff = blockIdx.y * 8;
  const int t = threadIdx.x;
  const int g = __builtin_amdgcn_readfirstlane(t >> 6);
  const int ln = t & 63;
  float* kw = smem + g * 2560;
  const float* Wb = Wq + (size_t)(jt * 64) * HH;
  const int srow = ln >> 2, sc = ln & 3;

  float acc[8];
#pragma unroll
  for (int c = 0; c < 8; c++) acc[c] = 0.f;
  float4 pf[4];
#pragma unroll
  for (int p = 0; p < 4; p++)
    pf[p] = *(const float4*)(Wb + (size_t)(p * 16 + srow) * HH + g * 16 + sc * 4);
  int buf = 0;
  for (int T = 0; T < 16; T++) {
    float* kb = kw + buf * 1280;
#pragma unroll
    for (int p = 0; p < 4; p++)
      *(float4*)(kb + ((p * 16 + srow) * 5 + sc) * 4) = pf[p];
    if (T < 15) {
      const int off = (T + 1) * 64 + g * 16 + sc * 4;
#pragma unroll
      for (int p = 0; p < 4; p++)
        pf[p] = *(const float4*)(Wb + (size_t)(p * 16 + srow) * HH + off);
    }
    const int i0 = T * 64 + g * 16;
#pragma unroll
    for (int u = 0; u < 4; u++) {
      float4 kv = *(const float4*)(kb + (ln * 5 + u) * 4);
      const float* q0 = qTT + (size_t)(i0 + u * 4 + 0) * BB + boff;
      const float* q1 = qTT + (size_t)(i0 + u * 4 + 1) * BB + boff;
      const float* q2 = qTT + (size_t)(i0 + u * 4 + 2) * BB + boff;
      const float* q3 = qTT + (size_t)(i0 + u * 4 + 3) * BB + boff;
#pragma unroll
      for (int c = 0; c < 8; c++) {
        acc[c] = fmaf(kv.x, q0[c], acc[c]);
        acc[c] = fmaf(kv.y, q1[c], acc[c]);
        acc[c] = fmaf(kv.z, q2[c], acc[c]);
        acc[c] = fmaf(kv.w, q3[c], acc[c]);
      }
    }
    buf ^= 1;
  }
  __syncthreads();
  float* part = smem;
  *(float4*)(part + g * 768 + ln * 12 + 0) =
      make_float4(acc[0], acc[1], acc[2], acc[3]);
  *(float4*)(part + g * 768 + ln * 12 + 4) =
      make_float4(acc[4], acc[5], acc[6], acc[7]);
  __syncthreads();
  const int j = t & 63, c0 = (t >> 6) * 2;
  float v0 = 0.f, v1 = 0.f;
#pragma unroll
  for (int g2 = 0; g2 < 4; g2++) {
    v0 += part[g2 * 768 + j * 12 + c0];
    v1 += part[g2 * 768 + j * 12 + c0 + 1];
  }
  const int jg = jt * 64 + j;
  const float bias = bq[jg];
  *(float2*)(qT + (size_t)jg * BB + boff + c0) =
      make_float2(v0 + bias, v1 + bias);
}

// ---------------------------------------------------------------------------
// K2: qkT[b][h][i] = SCALE * sum_d qT[h*64+d][b] * Wk[h*64+d][i]
// ---------------------------------------------------------------------------
__global__ __launch_bounds__(256) void k2_qk(const float* __restrict__ qT,
                                             const float* __restrict__ Wk,
                                             float* __restrict__ qkT) {
  const int h = blockIdx.y;
  const int it = blockIdx.x;
  const int il = threadIdx.x & 63;
  const int bs = __builtin_amdgcn_readfirstlane(threadIdx.x >> 6);
  const int i = it * 64 + il;
  const int boff = blockIdx.z * 64 + bs * 16;
  float acc[16];
#pragma unroll
  for (int k = 0; k < 16; k++) acc[k] = 0.f;
#pragma unroll 2
  for (int d = 0; d < DD; d++) {
    float wv = Wk[(size_t)(h * DD + d) * HH + i];
    const float* qrow = qT + (h * DD + d) * BB + boff;  // wave-uniform
#pragma unroll
    for (int k = 0; k < 16; k++) acc[k] = fmaf(qrow[k], wv, acc[k]);
  }
#pragma unroll
  for (int k = 0; k < 16; k++)
    qkT[(size_t)((boff + k) * NH + h) * HH + i] = SCALE * acc[k];
}

// ---------------------------------------------------------------------------
// K2b: relayout qkT[b][h][i] -> qkR[b][i>>2][16h][i&3].
// Stage: lds[h][0..255] = qkT[b][h][seg*256..+255] (coalesced dwordx4).
// Write: thread t: c = t&63 (= h*4+i3), i4g = t>>6; 16 i4-units each ->
// dst[i4l*64 + c] coalesced 256B/wave.  Row pitch 268: (12h+i3) mod 32
// spans 8 bank-quads -> 2-way conflict (free).  grid (4 seg, 256 b).
// ---------------------------------------------------------------------------
__global__ __launch_bounds__(256) void k2b_relayout(
    const float* __restrict__ qkT, float* __restrict__ qkR) {
  __shared__ float lds[16][268];
  const int b = blockIdx.y, seg = blockIdx.x;
  const int t = threadIdx.x;
  const int row = t >> 4, l16 = t & 15;
  const float* src = qkT + (size_t)b * 16384 + row * HH + seg * 256 + l16 * 16;
#pragma unroll
  for (int p = 0; p < 4; p++)
    *(float4*)(&lds[row][l16 * 16 + p * 4]) = *(const float4*)(src + p * 4);
  __syncthreads();
  const int c = t & 63;        // h*4 + i3
  const int i4g = t >> 6;      // 0..3
  const int h = c >> 2, i3 = c & 3;
  float* dst = qkR + (size_t)b * 16384 + seg * 4096;
#pragma unroll
  for (int jj = 0; jj < 16; jj++) {
    const int i4l = i4g * 16 + jj;
    dst[i4l * 64 + c] = lds[h][i4l * 4 + i3];
  }
}

// ---------------------------------------------------------------------------
// K3a: scores[b][h][l] = mask ? NEG_BIG : sum_i key[b][l][i]*qk[b][h][i]
// grid (4 lt, 256 b), block 256 = 4 waves.  NO LDS in the main loop:
//   - key: global->VGPR, lane owns row l, register double-buffered (vmcnt).
//   - qk: wave-uniform s_load_dwordx16 from qkR[b][i4][h][i3] (lgkmcnt holds
//     ONLY scalar loads -> no ds/scalar serialization).
// ---------------------------------------------------------------------------
__global__ __launch_bounds__(256, 4) void k3a_scores(
    const float* __restrict__ key, const int* __restrict__ mask,
    const float* __restrict__ qkR, float* __restrict__ scoresT) {
  __shared__ float part[5120];
  const int b = blockIdx.y;
  const int lt = blockIdx.x;
  const int t = threadIdx.x;
  const int g = __builtin_amdgcn_readfirstlane(t >> 6);
  const int ln = t & 63;
  const float* keyrow = key + ((size_t)(b * LL + lt * 64 + ln)) * HH + g * 256;
  const float* qkb = qkR + (size_t)b * 16384 + g * 4096;  // wave-uniform

  float acc[16];
#pragma unroll
  for (int h = 0; h < NH; h++) acc[h] = 0.f;

  float4 p0 = *(const float4*)(keyrow + 0);
  float4 p1 = *(const float4*)(keyrow + 4);
  float4 p2 = *(const float4*)(keyrow + 8);
  float4 p3 = *(const float4*)(keyrow + 12);

  for (int c = 0; c < 16; c++) {
    float4 k0 = p0, k1 = p1, k2 = p2, k3 = p3;
    if (c < 15) {
      const float* nx = keyrow + (c + 1) * 16;
      p0 = *(const float4*)(nx + 0);
      p1 = *(const float4*)(nx + 4);
      p2 = *(const float4*)(nx + 8);
      p3 = *(const float4*)(nx + 12);
    }
    const float* q = qkb + c * 256;
#pragma unroll
    for (int h = 0; h < NH; h++) {
      const float* qh = q + h * 4;
      acc[h] = fmaf(k0.x, qh[0], acc[h]);
      acc[h] = fmaf(k0.y, qh[1], acc[h]);
      acc[h] = fmaf(k0.z, qh[2], acc[h]);
      acc[h] = fmaf(k0.w, qh[3], acc[h]);
      acc[h] = fmaf(k1.x, qh[64], acc[h]);
      acc[h] = fmaf(k1.y, qh[65], acc[h]);
      acc[h] = fmaf(k1.z, qh[66], acc[h]);
      acc[h] = fmaf(k1.w, qh[67], acc[h]);
      acc[h] = fmaf(k2.x, qh[128], acc[h]);
      acc[h] = fmaf(k2.y, qh[129], acc[h]);
      acc[h] = fmaf(k2.z, qh[130], acc[h]);
      acc[h] = fmaf(k2.w, qh[131], acc[h]);
      acc[h] = fmaf(k3.x, qh[192], acc[h]);
      acc[h] = fmaf(k3.y, qh[193], acc[h]);
      acc[h] = fmaf(k3.z, qh[194], acc[h]);
      acc[h] = fmaf(k3.w, qh[195], acc[h]);
    }
  }

#pragma unroll
  for (int u = 0; u < 4; u++)
    *(float4*)(part + (g * 64 + ln) * 20 + u * 4) =
        make_float4(acc[u * 4], acc[u * 4 + 1], acc[u * 4 + 2], acc[u * 4 + 3]);
  __syncthreads();
  const int row = t & 63, hq = t >> 6;
  float4 s0 = *(const float4*)(part + (0 * 64 + row) * 20 + hq * 4);
  float4 s1 = *(const float4*)(part + (1 * 64 + row) * 20 + hq * 4);
  float4 s2 = *(const float4*)(part + (2 * 64 + row) * 20 + hq * 4);
  float4 s3 = *(const float4*)(part + (3 * 64 + row) * 20 + hq * 4);
  const int l = lt * 64 + row;
  const int mk = mask[b * LL + l];
  float o0 = mk ? NEG_BIG : (s0.x + s1.x + s2.x + s3.x);
  float o1 = mk ? NEG_BIG : (s0.y + s1.y + s2.y + s3.y);
  float o2 = mk ? NEG_BIG : (s0.z + s1.z + s2.z + s3.z);
  float o3 = mk ? NEG_BIG : (s0.w + s1.w + s2.w + s3.w);
  scoresT[(size_t)(b * NH + hq * 4 + 0) * LL + l] = o0;
  scoresT[(size_t)(b * NH + hq * 4 + 1) * LL + l] = o1;
  scoresT[(size_t)(b * NH + hq * 4 + 2) * LL + l] = o2;
  scoresT[(size_t)(b * NH + hq * 4 + 3) * LL + l] = o3;
}

// ---------------------------------------------------------------------------
// K3b: in-place softmax over attn[(b*16+h)][256].
// ---------------------------------------------------------------------------
__global__ __launch_bounds__(256) void k3b_softmax(float* __restrict__ attn) {
  const int r = blockIdx.x * 4 + (threadIdx.x >> 6);
  const int lane = threadIdx.x & 63;
  float* rowp = attn + (size_t)r * LL;
  float4 s = *(const float4*)(rowp + lane * 4);
  float m = fmaxf(fmaxf(s.x, s.y), fmaxf(s.z, s.w));
#pragma unroll
  for (int off = 32; off >= 1; off >>= 1) m = fmaxf(m, __shfl_xor(m, off));
  float ex = __expf(s.x - m), ey = __expf(s.y - m), ez = __expf(s.z - m),
        ew = __expf(s.w - m);
  float e = ex + ey + ez + ew;
#pragma unroll
  for (int off = 32; off >= 1; off >>= 1) e += __shfl_xor(e, off);
  float inv = 1.0f / e;
  *(float4*)(rowp + lane * 4) = make_float4(ex * inv, ey * inv, ez * inv, ew * inv);
}

// ---------------------------------------------------------------------------
// K3c: vbar[b][h][d] = sum_l attn[b][h][l] * value[b][l][d]
// ---------------------------------------------------------------------------
__global__ __launch_bounds__(256, 4) void k3c_vbar(
    const float* __restrict__ value, const float* __restrict__ attn,
    float* __restrict__ vbar) {
  const int b = blockIdx.y;
  const int d = blockIdx.x * 256 + threadIdx.x;
  const float* ab = attn + (size_t)b * NH * LL;
  const float* valb = value + (size_t)b * LL * HH + d;
  float acc[16];
#pragma unroll
  for (int h = 0; h < NH; h++) acc[h] = 0.f;
  for (int l0 = 0; l0 < LL; l0 += 16) {
    float vv[16];
#pragma unroll
    for (int k = 0; k < 16; k++) vv[k] = valb[(size_t)(l0 + k) * HH];
#pragma unroll
    for (int h = 0; h < NH; h++) {
      const float4* ar = (const float4*)(ab + h * LL + l0);  // uniform
      float4 a0 = ar[0], a1 = ar[1], a2 = ar[2], a3 = ar[3];
      acc[h] = fmaf(a0.x, vv[0], acc[h]);
      acc[h] = fmaf(a0.y, vv[1], acc[h]);
      acc[h] = fmaf(a0.z, vv[2], acc[h]);
      acc[h] = fmaf(a0.w, vv[3], acc[h]);
      acc[h] = fmaf(a1.x, vv[4], acc[h]);
      acc[h] = fmaf(a1.y, vv[5], acc[h]);
      acc[h] = fmaf(a1.z, vv[6], acc[h]);
      acc[h] = fmaf(a1.w, vv[7], acc[h]);
      acc[h] = fmaf(a2.x, vv[8], acc[h]);
      acc[h] = fmaf(a2.y, vv[9], acc[h]);
      acc[h] = fmaf(a2.z, vv[10], acc[h]);
      acc[h] = fmaf(a2.w, vv[11], acc[h]);
      acc[h] = fmaf(a3.x, vv[12], acc[h]);
      acc[h] = fmaf(a3.y, vv[13], acc[h]);
      acc[h] = fmaf(a3.z, vv[14], acc[h]);
      acc[h] = fmaf(a3.w, vv[15], acc[h]);
    }
  }
#pragma unroll
  for (int h = 0; h < NH; h++)
    vbar[((size_t)b * NH + h) * HH + d] = acc[h];
}

// ---------------------------------------------------------------------------
// K4: ctxT[j][b] = bv[j] + sum_i vbar[b][j>>6][i] * Wv[j][i]
// ---------------------------------------------------------------------------
__global__ __launch_bounds__(256) void k4_ctx(const float* __restrict__ Wv,
                                              const float* __restrict__ vbarT,
                                              const float* __restrict__ bv,
                                              float* __restrict__ ctxT) {
  __shared__ float smem[10240];
  const int jt = blockIdx.x;
  const int boff = blockIdx.y * 8;
  const int t = threadIdx.x;
  const int g = __builtin_amdgcn_readfirstlane(t >> 6);
  const int ln = t & 63;
  float* kw = smem + g * 2560;
  const float* Wb = Wv + (size_t)(jt * 64) * HH;
  const float* vt = vbarT + (size_t)jt * HH * BB;
  const int srow = ln >> 2, sc = ln & 3;

  float acc[8];
#pragma unroll
  for (int c = 0; c < 8; c++) acc[c] = 0.f;
  float4 pf[4];
#pragma unroll
  for (int p = 0; p < 4; p++)
    pf[p] = *(const float4*)(Wb + (size_t)(p * 16 + srow) * HH + g * 16 + sc * 4);
  int buf = 0;
  for (int T = 0; T < 16; T++) {
    float* kb = kw + buf * 1280;
#pragma unroll
    for (int p = 0; p < 4; p++)
      *(float4*)(kb + ((p * 16 + srow) * 5 + sc) * 4) = pf[p];
    if (T < 15) {
      const int off = (T + 1) * 64 + g * 16 + sc * 4;
#pragma unroll
      for (int p = 0; p < 4; p++)
        pf[p] = *(const float4*)(Wb + (size_t)(p * 16 + srow) * HH + off);
    }
    const int i0 = T * 64 + g * 16;
#pragma unroll
    for (int u = 0; u < 4; u++) {
      float4 kv = *(const float4*)(kb + (ln * 5 + u) * 4);
      const float* q0 = vt + (size_t)(i0 + u * 4 + 0) * BB + boff;
      const float* q1 = vt + (size_t)(i0 + u * 4 + 1) * BB + boff;
      const float* q2 = vt + (size_t)(i0 + u * 4 + 2) * BB + boff;
      const float* q3 = vt + (size_t)(i0 + u * 4 + 3) * BB + boff;
#pragma unroll
      for (int c = 0; c < 8; c++) {
        acc[c] = fmaf(kv.x, q0[c], acc[c]);
        acc[c] = fmaf(kv.y, q1[c], acc[c]);
        acc[c] = fmaf(kv.z, q2[c], acc[c]);
        acc[c] = fmaf(kv.w, q3[c], acc[c]);
      }
    }
    buf ^= 1;
  }
  __syncthreads();
  float* part = smem;
  *(float4*)(part + g * 768 + ln * 12 + 0) =
      make_float4(acc[0], acc[1], acc[2], acc[3]);
  *(float4*)(part + g * 768 + ln * 12 + 4) =
      make_float4(acc[4], acc[5], acc[6], acc[7]);
  __syncthreads();
  const int j = t & 63, c0 = (t >> 6) * 2;
  float v0 = 0.f, v1 = 0.f;
#pragma unroll
  for (int g2 = 0; g2 < 4; g2++) {
    v0 += part[g2 * 768 + j * 12 + c0];
    v1 += part[g2 * 768 + j * 12 + c0 + 1];
  }
  const int jg = jt * 64 + j;
  const float bias = bv[jg];
  *(float2*)(ctxT + (size_t)jg * BB + boff + c0) =
      make_float2(v0 + bias, v1 + bias);
}

// ---------------------------------------------------------------------------
// K5: xws[b][j] = query[b][j] + bf[j] + sum_i ctxT[i][b] * Wf[j][i]
// ---------------------------------------------------------------------------
__global__ __launch_bounds__(256) void k5_outproj(
    const float* __restrict__ Wf, const float* __restrict__ ctxT,
    const float* __restrict__ bf, const float* __restrict__ query,
    float* __restrict__ xws) {
  __shared__ float smem[10240];
  const int jt = blockIdx.x;
  const int boff = blockIdx.y * 8;
  const int t = threadIdx.x;
  const int g = __builtin_amdgcn_readfirstlane(t >> 6);
  const int ln = t & 63;
  float* kw = smem + g * 2560;
  const float* Wb = Wf + (size_t)(jt * 64) * HH;
  const int srow = ln >> 2, sc = ln & 3;

  float acc[8];
#pragma unroll
  for (int c = 0; c < 8; c++) acc[c] = 0.f;
  float4 pf[4];
#pragma unroll
  for (int p = 0; p < 4; p++)
    pf[p] = *(const float4*)(Wb + (size_t)(p * 16 + srow) * HH + g * 16 + sc * 4);
  int buf = 0;
  for (int T = 0; T < 16; T++) {
    float* kb = kw + buf * 1280;
#pragma unroll
    for (int p = 0; p < 4; p++)
      *(float4*)(kb + ((p * 16 + srow) * 5 + sc) * 4) = pf[p];
    if (T < 15) {
      const int off = (T + 1) * 64 + g * 16 + sc * 4;
#pragma unroll
      for (int p = 0; p < 4; p++)
        pf[p] = *(const float4*)(Wb + (size_t)(p * 16 + srow) * HH + off);
    }
    const int i0 = T * 64 + g * 16;
#pragma unroll
    for (int u = 0; u < 4; u++) {
      float4 kv = *(const float4*)(kb + (ln * 5 + u) * 4);
      const float* q0 = ctxT + (size_t)(i0 + u * 4 + 0) * BB + boff;
      const float* q1 = ctxT + (size_t)(i0 + u * 4 + 1) * BB + boff;
      const float* q2 = ctxT + (size_t)(i0 + u * 4 + 2) * BB + boff;
      const float* q3 = ctxT + (size_t)(i0 + u * 4 + 3) * BB + boff;
#pragma unroll
      for (int c = 0; c < 8; c++) {
        acc[c] = fmaf(kv.x, q0[c], acc[c]);
        acc[c] = fmaf(kv.y, q1[c], acc[c]);
        acc[c] = fmaf(kv.z, q2[c], acc[c]);
        acc[c] = fmaf(kv.w, q3[c], acc[c]);
      }
    }
    buf ^= 1;
  }
  __syncthreads();
  float* part = smem;
  *(float4*)(part + g * 768 + ln * 12 + 0) =
      make_float4(acc[0], acc[1], acc[2], acc[3]);
  *(float4*)(part + g * 768 + ln * 12 + 4) =
      make_float4(acc[4], acc[5], acc[6], acc[7]);
  __syncthreads();
  const int j = t & 63, c0 = (t >> 6) * 2;
  float v0 = 0.f, v1 = 0.f;
#pragma unroll
  for (int g2 = 0; g2 < 4; g2++) {
    v0 += part[g2 * 768 + j * 12 + c0];
    v1 += part[g2 * 768 + j * 12 + c0 + 1];
  }
  const int jg = jt * 64 + j;
  const float bias = bf[jg];
  const int b0 = boff + c0;
  xws[(size_t)b0 * HH + jg] = v0 + bias + query[(size_t)b0 * HH + jg];
  xws[(size_t)(b0 + 1) * HH + jg] = v1 + bias + query[(size_t)(b0 + 1) * HH + jg];
}

// ---------------------------------------------------------------------------
// K6: LayerNorm over H, two-pass (exact), block per b.
// ---------------------------------------------------------------------------
__global__ __launch_bounds__(256) void k6_ln(const float* __restrict__ xws,
                                             const float* __restrict__ gamma,
                                             const float* __restrict__ beta,
                                             float* __restrict__ out0) {
  __shared__ float rb[8];
  const int b = blockIdx.x, t = threadIdx.x;
  float4 v = *(const float4*)(xws + (size_t)b * HH + 4 * t);
  float s = v.x + v.y + v.z + v.w;
#pragma unroll
  for (int off = 32; off >= 1; off >>= 1) s += __shfl_xor(s, off);
  if ((t & 63) == 0) rb[t >> 6] = s;
  __syncthreads();
  float mu = (rb[0] + rb[1] + rb[2] + rb[3]) * (1.0f / HH);
  float dx = v.x - mu, dy = v.y - mu, dz = v.z - mu, dw = v.w - mu;
  float q = dx * dx + dy * dy + dz * dz + dw * dw;
#pragma unroll
  for (int off = 32; off >= 1; off >>= 1) q += __shfl_xor(q, off);
  if ((t & 63) == 0) rb[4 + (t >> 6)] = q;
  __syncthreads();
  float var = (rb[4] + rb[5] + rb[6] + rb[7]) * (1.0f / HH);
  float rs = rsqrtf(var + LN_EPS);
  float4 gm = *(const float4*)(gamma + 4 * t);
  float4 bt = *(const float4*)(beta + 4 * t);
  float4 o;
  o.x = dx * rs * gm.x + bt.x;
  o.y = dy * rs * gm.y + bt.y;
  o.z = dz * rs * gm.z + bt.z;
  o.w = dw * rs * gm.w + bt.w;
  *(float4*)(out0 + (size_t)b * HH + 4 * t) = o;
}

extern "C" void kernel_launch(void* const* d_in, const int* in_sizes, int n_in,
                              void* d_out, int out_size, void* d_ws,
                              size_t ws_size, hipStream_t stream) {
  (void)in_sizes; (void)n_in; (void)out_size; (void)ws_size;
  const float* key = (const float*)d_in[0];
  const float* value = (const float*)d_in[1];
  const float* query = (const float*)d_in[2];
  const int* mask = (const int*)d_in[3];
  const float* Wq = (const float*)d_in[4];
  const float* bq = (const float*)d_in[5];
  const float* Wk = (const float*)d_in[6];
  // d_in[7] = bk: softmax-invariant, dropped
  const float* Wv = (const float*)d_in[8];
  const float* bv = (const float*)d_in[9];
  const float* Wf = (const float*)d_in[10];
  const float* bf = (const float*)d_in[11];
  const float* gamma = (const float*)d_in[12];
  const float* beta = (const float*)d_in[13];

  float* out0 = (float*)d_out;      // (B,1,H)
  float* attnOut = out0 + BB * HH;  // (B*NH,1,L): scores -> softmax in place

  // ws lifetimes: qT dead after k2 (ctxT reuses); qTT dead after k1 (xws
  // reuses); qkT dead after k2b (vbar reuses); qkR dead after k3a.
  char* ws = (char*)d_ws;
  float* qT = (float*)(ws);                  //  1 MB [j][b]
  float* qTT = (float*)(ws + (1 << 20));     //  1 MB [i][b]
  float* qkT = (float*)(ws + (2 << 20));     // 16 MB [b][h][i]
  float* qkR = (float*)(ws + (18 << 20));    // 16 MB [b][i4][h][i3]
  float* vbar = (float*)(ws + (2 << 20));    // 16 MB [b][h][i] (over qkT)
  float* vbarT = (float*)(ws + (34 << 20));  // 16 MB [h][i][b]
  float* ctxT = (float*)(ws);                //  1 MB [j][b]   (over qT)
  float* xws = (float*)(ws + (1 << 20));     //  1 MB [b][j]   (over qTT)

  t_tr<<<dim3(16, 4, 1), 256, 0, stream>>>(query, qTT, HH, BB, 0, 0);
  k1_qproj<<<dim3(16, 32), 256, 0, stream>>>(Wq, qTT, bq, qT);
  k2_qk<<<dim3(16, 16, 4), 256, 0, stream>>>(qT, Wk, qkT);
  k2b_relayout<<<dim3(4, 256), 256, 0, stream>>>(qkT, qkR);
  k3a_scores<<<dim3(4, 256), 256, 0, stream>>>(key, mask, qkR, attnOut);
  k3b_softmax<<<dim3(1024), 256, 0, stream>>>(attnOut);
  k3c_vbar<<<dim3(4, 256), 256, 0, stream>>>(value, attnOut, vbar);
  t_tr<<<dim3(16, 4, 16), 256, 0, stream>>>(vbar, vbarT, NH * HH, BB, HH,
                                            HH * BB);
  k4_ctx<<<dim3(16, 32), 256, 0, stream>>>(Wv, vbarT, bv, ctxT);
  k5_outproj<<<dim3(16, 32), 256, 0, stream>>>(Wf, ctxT, bf, query, xws);
  k6_ln<<<dim3(256), 256, 0, stream>>>(xws, gamma, beta, out0);
}